// Round 4
// baseline (3065.739 us; speedup 1.0000x reference)
//
#include <hip/hip_runtime.h>
#include <hip/hip_bf16.h>
#include <cmath>

typedef unsigned int u32;
typedef unsigned short u16;
typedef _Float16 f16;
typedef f16 h2 __attribute__((ext_vector_type(2)));
typedef f16 h8 __attribute__((ext_vector_type(8)));
typedef short bf16x8 __attribute__((ext_vector_type(8)));
typedef float f32x4 __attribute__((ext_vector_type(4)));

// ---------- sizes ----------
#define Bn 64
#define Tn 1024
#define IDIM 80
#define Hn 256
#define G3 768           // 3*H
#define STOK 5
#define SDIM 128
#define MROWS (Bn*Tn)    // 65536

// ---------- helpers ----------
__device__ __forceinline__ float bf2f(u16 v) { return __uint_as_float(((u32)v) << 16); }
__device__ __forceinline__ u16 f2bf(float f) {
  u32 x = __float_as_uint(f);
  return (u16)((x + 0x7FFFu + ((x >> 16) & 1u)) >> 16);   // RNE
}
__device__ __forceinline__ float frcp(float x) {
#if __has_builtin(__builtin_amdgcn_rcpf)
  return __builtin_amdgcn_rcpf(x);
#else
  return 1.f / x;
#endif
}
__device__ __forceinline__ float fsig(float x) { return frcp(1.f + __expf(-x)); }
__device__ __forceinline__ float ftanh(float x) { return 1.f - 2.f * frcp(1.f + __expf(2.f * x)); }

// ---------- conversion kernels ----------
__global__ void k_cvt_bf16(const float* __restrict__ in, u16* __restrict__ out, int n) {
  int i = blockIdx.x * blockDim.x + threadIdx.x;
  int st = gridDim.x * blockDim.x;
  for (; i < n; i += st) out[i] = f2bf(in[i]);
}

// Pack Whh[768][256] f32 into per-thread MFMA A-fragments (f16 pairs).
// Thread tid (wave=tid>>6, lane=tid&63) holds 32 frags: (g=0..3, s=0..7).
//   frag (g,s), reg r=0..3: u32 = pack( W[j][c], W[j][c+1] )
//   j = (wave*4+g)*16 + (lane&15),  c = 32*s + (lane>>4)*8 + 2*r
// Stored at out[tid*128 + (s*4+g)*4 + r].
__global__ void k_prep_whh(const float* __restrict__ W, u32* __restrict__ out) {
  int idx = blockIdx.x * 256 + threadIdx.x;
  if (idx >= G3 * 128) return;
  int tid = idx >> 7, rest = idx & 127;
  int wave = tid >> 6, lane = tid & 63;
  int s = rest >> 4, g = (rest >> 2) & 3, r = rest & 3;
  int j = (wave * 4 + g) * 16 + (lane & 15);
  int c = 32 * s + (lane >> 4) * 8 + 2 * r;
  union { f16 h; u16 u; } a, b;
  a.h = (f16)W[j * Hn + c];
  b.h = (f16)W[j * Hn + c + 1];
  out[idx] = ((u32)b.u << 16) | (u32)a.u;
}

// ---------- k/v projection (tiny: 5x256 each) ----------
__global__ __launch_bounds__(256) void k_kv(const float* __restrict__ st,
                                            const float* __restrict__ kw,
                                            const float* __restrict__ vw,
                                            const float* __restrict__ inb,
                                            float* __restrict__ kv) {
  int e = threadIdx.x;   // 0..255
  for (int s = 0; s < STOK; ++s) {
    float ak = inb[Hn + e], av = inb[2 * Hn + e];
    for (int d = 0; d < SDIM; ++d) {
      float x = st[s * SDIM + d];
      ak += x * kw[e * SDIM + d];
      av += x * vw[e * SDIM + d];
    }
    kv[s * Hn + e] = ak;
    kv[STOK * Hn + s * Hn + e] = av;
  }
}

// ---------- MFMA GEMM: C[m][n] = scale*(sum_k A[m][k]*B[n][k] + bias[n]) ----------
template <bool OUT_BF16>
__global__ __launch_bounds__(256) void k_gemm_bt(const u16* __restrict__ A,
                                                 const u16* __restrict__ B,
                                                 const float* __restrict__ bias,
                                                 float scale, void* __restrict__ Cout,
                                                 int M, int N, int K) {
  constexpr int BM = 128, BN = 128, BK = 32, LDT = 40;
  __shared__ __align__(16) u16 As[BM * LDT];
  __shared__ __align__(16) u16 Bs[BN * LDT];
  const int tid = threadIdx.x;
  const int bm0 = blockIdx.x * BM;
  const int bn0 = blockIdx.y * BN;
  const int lane = tid & 63;
  const int wave = tid >> 6;
  const int wm = (wave & 1) * 64;
  const int wn = (wave >> 1) * 64;
  const int lr = lane & 15;
  const int kg = lane >> 4;
  const int srow = tid >> 1, sch = tid & 1;

  f32x4 acc[4][4] = {};

  for (int k0 = 0; k0 < K; k0 += BK) {
    {
      const u16* gp = A + (size_t)(bm0 + srow) * K + k0 + sch * 16;
      u16* lp = &As[srow * LDT + sch * 16];
      if (k0 + BK <= K) {
        *(uint4*)lp = *(const uint4*)gp;
        *(uint4*)(lp + 8) = *(const uint4*)(gp + 8);
      } else {
        for (int i = 0; i < 16; ++i) {
          int k = k0 + sch * 16 + i;
          lp[i] = (k < K) ? gp[i] : (u16)0;
        }
      }
    }
    {
      const u16* gp = B + (size_t)(bn0 + srow) * K + k0 + sch * 16;
      u16* lp = &Bs[srow * LDT + sch * 16];
      if (k0 + BK <= K) {
        *(uint4*)lp = *(const uint4*)gp;
        *(uint4*)(lp + 8) = *(const uint4*)(gp + 8);
      } else {
        for (int i = 0; i < 16; ++i) {
          int k = k0 + sch * 16 + i;
          lp[i] = (k < K) ? gp[i] : (u16)0;
        }
      }
    }
    __syncthreads();

    bf16x8 af[4], bfr[4];
#pragma unroll
    for (int mi = 0; mi < 4; ++mi)
      af[mi] = *(const bf16x8*)&As[(wm + mi * 16 + lr) * LDT + kg * 8];
#pragma unroll
    for (int ni = 0; ni < 4; ++ni)
      bfr[ni] = *(const bf16x8*)&Bs[(wn + ni * 16 + lr) * LDT + kg * 8];
#pragma unroll
    for (int mi = 0; mi < 4; ++mi)
#pragma unroll
      for (int ni = 0; ni < 4; ++ni)
        acc[mi][ni] = __builtin_amdgcn_mfma_f32_16x16x32_bf16(af[mi], bfr[ni], acc[mi][ni], 0, 0, 0);
    __syncthreads();
  }

#pragma unroll
  for (int mi = 0; mi < 4; ++mi)
#pragma unroll
    for (int ni = 0; ni < 4; ++ni)
#pragma unroll
      for (int r = 0; r < 4; ++r) {
        int row = bm0 + wm + mi * 16 + kg * 4 + r;
        int col = bn0 + wn + ni * 16 + lr;
        float v = acc[mi][ni][r];
        if (bias) v += bias[col];
        v *= scale;
        if (OUT_BF16)
          ((u16*)Cout)[(size_t)row * N + col] = f2bf(v);
        else
          ((float*)Cout)[(size_t)row * N + col] = v;
      }
}

// ---------- GRU scan (MFMA recurrent matvec) ----------
// One workgroup (768 thr = 12 waves) per batch chain. Per step:
//   gh = Whh . h  via 384 mfma_f32_16x16x32_f16: wave w covers j-groups
//   g_abs = w*4+g (16 j each), K=256 as 8 chained k-slices. A = W frags
//   (register-resident, prep-swizzled), B = h broadcast to all 16 cols
//   (1 ds_read_b128 per k-slice from linear hsh). D cols identical; lanes
//   l&15==0 write rows (l>>4)*4+r as one ds_write_b128 per j-group.
// MFMA issue/step: 96/SIMD * ~4.85cy = ~466 cy vs ~2800 cy VALU version.
__global__ void __launch_bounds__(768)
__attribute__((amdgpu_waves_per_eu(3, 3)))
k_gru(const u32* __restrict__ Wp,
      const float* __restrict__ bhh,
      const u16* __restrict__ xg,
      u16* __restrict__ outs) {
  const int tid = threadIdx.x;
  const int b = blockIdx.x;
  const int lane = tid & 63;
  const int wave = tid >> 6;
  __shared__ __align__(16) f16 hsh[Hn];    // linear h (f16)
  __shared__ __align__(16) float ght[G3];  // gh scratch
  __shared__ float xls[G3];                // x-gate stash for current step

  // W fragments -> registers, pinned
  u32 wv[128];
  {
    const uint4* wp = (const uint4*)(Wp + (size_t)tid * 128);
#pragma unroll
    for (int i = 0; i < 32; ++i) ((uint4*)wv)[i] = wp[i];
  }
#pragma unroll
  for (int i = 0; i < 128; ++i) asm volatile("" : "+v"(wv[i]));

  // gate-thread constants and state
  float b0 = 0.f, b1 = 0.f, b2 = 0.f;
  if (tid < Hn) { b0 = bhh[tid]; b1 = bhh[tid + Hn]; b2 = bhh[tid + 2 * Hn]; }
  float hreg = 0.f;
  if (tid < 128) ((h2*)hsh)[tid] = h2{(f16)0.f, (f16)0.f};

  const u16* xgb = xg + (size_t)b * Tn * G3;
  u16* ob = outs + (size_t)b * Tn * Hn;
  const f16* hb = hsh + (lane >> 4) * 8;   // per-lane B-frag base
  const int gwr = (lane & 15) == 0;        // D writer lanes
  const int dbase = wave * 64 + (lane >> 4) * 4;  // ght float index for g=0

  float xcur = bf2f(xgb[tid]);   // x for t=0
  __syncthreads();

  for (int t = 0; t < Tn; ++t) {
    // stash this step's x (gate threads read 3 of them after the barrier)
    xls[tid] = xcur;
    // prefetch next step's x (independent of h; hides under MFMA phase)
    int tn = (t + 1 < Tn) ? t + 1 : t;
    float xnext = bf2f(xgb[(size_t)tn * G3 + tid]);

    // MFMA phase: gh = Whh . h
    f32x4 a0 = {}, a1 = {}, a2 = {}, a3 = {};
#pragma unroll
    for (int s = 0; s < 8; ++s) {
      h8 bb = *(const h8*)(hb + s * 32);
      h8 w0 = __builtin_bit_cast(h8, ((const uint4*)wv)[s * 4 + 0]);
      h8 w1 = __builtin_bit_cast(h8, ((const uint4*)wv)[s * 4 + 1]);
      h8 w2 = __builtin_bit_cast(h8, ((const uint4*)wv)[s * 4 + 2]);
      h8 w3 = __builtin_bit_cast(h8, ((const uint4*)wv)[s * 4 + 3]);
      a0 = __builtin_amdgcn_mfma_f32_16x16x32_f16(w0, bb, a0, 0, 0, 0);
      a1 = __builtin_amdgcn_mfma_f32_16x16x32_f16(w1, bb, a1, 0, 0, 0);
      a2 = __builtin_amdgcn_mfma_f32_16x16x32_f16(w2, bb, a2, 0, 0, 0);
      a3 = __builtin_amdgcn_mfma_f32_16x16x32_f16(w3, bb, a3, 0, 0, 0);
    }
    if (gwr) {
      *(f32x4*)(ght + dbase) = a0;
      *(f32x4*)(ght + dbase + 16) = a1;
      *(f32x4*)(ght + dbase + 32) = a2;
      *(f32x4*)(ght + dbase + 48) = a3;
    }
    __syncthreads();

    // gate phase (256 threads)
    if (tid < Hn) {
      float gr = ght[tid] + b0;
      float gz = ght[tid + Hn] + b1;
      float gn = ght[tid + 2 * Hn] + b2;
      float r = fsig(xls[tid] + gr);
      float z = fsig(xls[tid + Hn] + gz);
      float n = ftanh(xls[tid + 2 * Hn] + r * gn);
      hreg = (1.f - z) * n + z * hreg;
      ob[(size_t)t * Hn + tid] = f2bf(hreg);
      hsh[tid] = (f16)hreg;
    }
    __syncthreads();
    xcur = xnext;
  }
}

// ---------- attention over 5 style tokens (thread per (b,t) row) ----------
__global__ __launch_bounds__(256) void k_attn(const u16* __restrict__ q,
                                              const float* __restrict__ kv,
                                              u16* __restrict__ ctx) {
  __shared__ float ks[STOK * Hn], vs[STOK * Hn];
  int tid = threadIdx.x;
  for (int i = tid; i < STOK * Hn; i += 256) {
    ks[i] = kv[i];
    vs[i] = kv[STOK * Hn + i];
  }
  __syncthreads();
  size_t row = (size_t)blockIdx.x * 256 + tid;
  const u16* qr = q + row * Hn;
  u16* cr = ctx + row * Hn;
#pragma unroll
  for (int h = 0; h < 4; ++h) {
    float sc[STOK] = {0.f, 0.f, 0.f, 0.f, 0.f};
    for (int d = 0; d < 64; ++d) {
      float qv = bf2f(qr[h * 64 + d]);
#pragma unroll
      for (int s = 0; s < STOK; ++s) sc[s] += qv * ks[s * Hn + h * 64 + d];
    }
    float m = sc[0];
#pragma unroll
    for (int s = 1; s < STOK; ++s) m = fmaxf(m, sc[s]);
    float p[STOK], sum = 0.f;
#pragma unroll
    for (int s = 0; s < STOK; ++s) { p[s] = __expf(sc[s] - m); sum += p[s]; }
    float inv = 1.f / sum;
    for (int e = 0; e < 64; ++e) {
      float c = 0.f;
#pragma unroll
      for (int s = 0; s < STOK; ++s) c += p[s] * vs[s * Hn + h * 64 + e];
      cr[h * 64 + e] = f2bf(c * inv);
    }
  }
}

// ---------- workspace layout (bytes) ----------
#define WS_XG   ((size_t)0)                         // [B][T][768] bf16 = 100,663,296
#define WS_O0   ((size_t)100663296)                 // [B][T][256] bf16 = 33,554,432
#define WS_O1   ((size_t)134217728)                 // 33,554,432
#define WS_FB   ((size_t)167772160)                 // feats bf16 = 10,485,760
#define WS_W0   ((size_t)178257920)                 // Wih0 bf16 = 122,880
#define WS_W1   ((size_t)178380800)                 // Wih1 bf16 = 393,216
#define WS_QW   ((size_t)178774016)                 // q_w bf16 = 131,072
#define WS_OW   ((size_t)178905088)                 // out_w bf16 = 131,072
#define WS_H0   ((size_t)179036160)                 // Whh0 prepped u32 = 393,216
#define WS_H1   ((size_t)179429376)                 // Whh1 prepped u32 = 393,216
#define WS_KV   ((size_t)179822592)                 // k,v f32 = 10,240
#define WS_QB   ((size_t)0)                         // q aliases dead xg
#define WS_CTX  ((size_t)33554432)                  // ctx aliases dead xg

extern "C" void kernel_launch(void* const* d_in, const int* in_sizes, int n_in,
                              void* d_out, int out_size, void* d_ws, size_t ws_size,
                              hipStream_t stream) {
  const float* feats = (const float*)d_in[0];
  const float* style = (const float*)d_in[1];
  const float* Wih0 = (const float*)d_in[2];
  const float* Whh0 = (const float*)d_in[3];
  const float* bih0 = (const float*)d_in[4];
  const float* bhh0 = (const float*)d_in[5];
  const float* Wih1 = (const float*)d_in[6];
  const float* Whh1 = (const float*)d_in[7];
  const float* bih1 = (const float*)d_in[8];
  const float* bhh1 = (const float*)d_in[9];
  const float* q_w = (const float*)d_in[10];
  const float* k_w = (const float*)d_in[11];
  const float* v_w = (const float*)d_in[12];
  const float* in_b = (const float*)d_in[13];
  const float* out_w = (const float*)d_in[14];
  const float* out_b = (const float*)d_in[15];

  char* ws = (char*)d_ws;
  u16* xg = (u16*)(ws + WS_XG);
  u16* o0 = (u16*)(ws + WS_O0);
  u16* o1 = (u16*)(ws + WS_O1);
  u16* fb = (u16*)(ws + WS_FB);
  u16* w0 = (u16*)(ws + WS_W0);
  u16* w1 = (u16*)(ws + WS_W1);
  u16* qw = (u16*)(ws + WS_QW);
  u16* ow = (u16*)(ws + WS_OW);
  u32* h0 = (u32*)(ws + WS_H0);
  u32* h1 = (u32*)(ws + WS_H1);
  float* kv = (float*)(ws + WS_KV);
  u16* qb = (u16*)(ws + WS_QB);
  u16* ctx = (u16*)(ws + WS_CTX);

  auto cvgrid = [](int n) { int g = (n + 255) / 256; return g > 2048 ? 2048 : g; };

  // conversions / weight prep
  k_cvt_bf16<<<cvgrid(MROWS * IDIM), 256, 0, stream>>>(feats, fb, MROWS * IDIM);
  k_cvt_bf16<<<cvgrid(G3 * IDIM), 256, 0, stream>>>(Wih0, w0, G3 * IDIM);
  k_cvt_bf16<<<cvgrid(G3 * Hn), 256, 0, stream>>>(Wih1, w1, G3 * Hn);
  k_cvt_bf16<<<cvgrid(Hn * Hn), 256, 0, stream>>>(q_w, qw, Hn * Hn);
  k_cvt_bf16<<<cvgrid(Hn * Hn), 256, 0, stream>>>(out_w, ow, Hn * Hn);
  k_prep_whh<<<(G3 * 128 + 255) / 256, 256, 0, stream>>>(Whh0, h0);
  k_prep_whh<<<(G3 * 128 + 255) / 256, 256, 0, stream>>>(Whh1, h1);

  k_kv<<<1, 256, 0, stream>>>(style, k_w, v_w, in_b, kv);

  dim3 g768(MROWS / 128, G3 / 128);
  dim3 g256(MROWS / 128, Hn / 128);

  // layer 0
  k_gemm_bt<true><<<g768, 256, 0, stream>>>(fb, w0, bih0, 1.f, xg, MROWS, G3, IDIM);
  k_gru<<<Bn, G3, 0, stream>>>(h0, bhh0, xg, o0);
  // layer 1
  k_gemm_bt<true><<<g768, 256, 0, stream>>>(o0, w1, bih1, 1.f, xg, MROWS, G3, Hn);
  k_gru<<<Bn, G3, 0, stream>>>(h1, bhh1, xg, o1);
  // attention
  k_gemm_bt<true><<<g256, 256, 0, stream>>>(o1, qw, in_b, 0.125f, qb, MROWS, Hn, Hn);
  k_attn<<<MROWS / 256, 256, 0, stream>>>(qb, kv, ctx);
  // output projection
  k_gemm_bt<false><<<g256, 256, 0, stream>>>(ctx, ow, out_b, 1.f, d_out, MROWS, Hn, Hn);
}

// Round 5
// 2579.888 us; speedup vs baseline: 1.1883x; 1.1883x over previous
//
#include <hip/hip_runtime.h>
#include <hip/hip_bf16.h>
#include <cmath>

typedef unsigned int u32;
typedef unsigned short u16;
typedef _Float16 f16;
typedef f16 h2 __attribute__((ext_vector_type(2)));
typedef f16 h8 __attribute__((ext_vector_type(8)));
typedef short bf16x8 __attribute__((ext_vector_type(8)));
typedef float f32x4 __attribute__((ext_vector_type(4)));
typedef u16 u16x4 __attribute__((ext_vector_type(4)));

// ---------- sizes ----------
#define Bn 64
#define Tn 1024
#define IDIM 80
#define Hn 256
#define G3 768           // 3*H
#define STOK 5
#define SDIM 128
#define MROWS (Bn*Tn)    // 65536

// ---------- helpers ----------
__device__ __forceinline__ float bf2f(u16 v) { return __uint_as_float(((u32)v) << 16); }
__device__ __forceinline__ u16 f2bf(float f) {
  u32 x = __float_as_uint(f);
  return (u16)((x + 0x7FFFu + ((x >> 16) & 1u)) >> 16);   // RNE
}
__device__ __forceinline__ float fdot2f(h2 a, h2 b, float c) {
#if __has_builtin(__builtin_amdgcn_fdot2)
  return __builtin_amdgcn_fdot2(a, b, c, false);
#else
  return c + (float)a[0] * (float)b[0] + (float)a[1] * (float)b[1];
#endif
}
__device__ __forceinline__ float frcp(float x) {
#if __has_builtin(__builtin_amdgcn_rcpf)
  return __builtin_amdgcn_rcpf(x);
#else
  return 1.f / x;
#endif
}
__device__ __forceinline__ float fsig(float x) { return frcp(1.f + __expf(-x)); }
__device__ __forceinline__ float ftanh(float x) { return 1.f - 2.f * frcp(1.f + __expf(2.f * x)); }
// quad (4-lane) sum via DPP quad_perm
__device__ __forceinline__ float qsum(float v) {
  v += __int_as_float(__builtin_amdgcn_mov_dpp(__float_as_int(v), 0xB1, 0xF, 0xF, true)); // xor 1
  v += __int_as_float(__builtin_amdgcn_mov_dpp(__float_as_int(v), 0x4E, 0xF, 0xF, true)); // xor 2
  return v;
}
#define W2(x) __builtin_bit_cast(h2, (x))

// LDS-only barrier: commit prior ds ops, barrier, fence scheduling both sides.
// Raw s_barrier (NOT __syncthreads) so in-flight global loads/stores survive.
__device__ __forceinline__ void lds_barrier() {
  asm volatile("s_waitcnt lgkmcnt(0)" ::: "memory");
  __builtin_amdgcn_sched_barrier(0);
  __builtin_amdgcn_s_barrier();
  __builtin_amdgcn_sched_barrier(0);
}

// ---------- conversion kernels ----------
__global__ void k_cvt_bf16(const float* __restrict__ in, u16* __restrict__ out, int n) {
  int i = blockIdx.x * blockDim.x + threadIdx.x;
  int st = gridDim.x * blockDim.x;
  for (; i < n; i += st) out[i] = f2bf(in[i]);
}

// Pack Whh[768][256] f32 -> per-thread quad-sliced f16 pairs (R3 layout):
// out u32 idx = tau*128 + s*32 + i*4 + p
//   = pack( W[(tau>>2)+192s][64*(tau&3)+8i+2p], [.. +1] )
__global__ void k_prep_whh(const float* __restrict__ W, u32* __restrict__ out) {
  int idx = blockIdx.x * 256 + threadIdx.x;
  if (idx >= G3 * 128) return;
  int tau = idx >> 7, rest = idx & 127;
  int s = rest >> 5, i2 = (rest >> 2) & 7, p = rest & 3;
  int r = (tau >> 2) + 192 * s;
  int c = 64 * (tau & 3) + 8 * i2 + 2 * p;
  union { f16 h; u16 u; } a, b;
  a.h = (f16)W[r * Hn + c];
  b.h = (f16)W[r * Hn + c + 1];
  out[idx] = ((u32)b.u << 16) | (u32)a.u;
}

// ---------- k/v projection ----------
__global__ __launch_bounds__(256) void k_kv(const float* __restrict__ st,
                                            const float* __restrict__ kw,
                                            const float* __restrict__ vw,
                                            const float* __restrict__ inb,
                                            float* __restrict__ kv) {
  int e = threadIdx.x;
  for (int s = 0; s < STOK; ++s) {
    float ak = inb[Hn + e], av = inb[2 * Hn + e];
    for (int d = 0; d < SDIM; ++d) {
      float x = st[s * SDIM + d];
      ak += x * kw[e * SDIM + d];
      av += x * vw[e * SDIM + d];
    }
    kv[s * Hn + e] = ak;
    kv[STOK * Hn + s * Hn + e] = av;
  }
}

// ---------- MFMA GEMM: C = scale*(A @ B^T + bias) ----------
// MODE 0: f32 out [M][N]; 1: bf16 out [M][N]; 2: bf16 out TRANSPOSED [B][N][T]
template <int MODE>
__global__ __launch_bounds__(256) void k_gemm_bt(const u16* __restrict__ A,
                                                 const u16* __restrict__ B,
                                                 const float* __restrict__ bias,
                                                 float scale, void* __restrict__ Cout,
                                                 int M, int N, int K) {
  constexpr int BM = 128, BN = 128, BK = 32, LDT = 40;
  __shared__ __align__(16) u16 As[BM * LDT];
  __shared__ __align__(16) u16 Bs[BN * LDT];
  const int tid = threadIdx.x;
  const int bm0 = blockIdx.x * BM;
  const int bn0 = blockIdx.y * BN;
  const int lane = tid & 63;
  const int wave = tid >> 6;
  const int wm = (wave & 1) * 64;
  const int wn = (wave >> 1) * 64;
  const int lr = lane & 15;
  const int kg = lane >> 4;
  const int srow = tid >> 1, sch = tid & 1;

  f32x4 acc[4][4] = {};

  for (int k0 = 0; k0 < K; k0 += BK) {
    {
      const u16* gp = A + (size_t)(bm0 + srow) * K + k0 + sch * 16;
      u16* lp = &As[srow * LDT + sch * 16];
      if (k0 + BK <= K) {
        *(uint4*)lp = *(const uint4*)gp;
        *(uint4*)(lp + 8) = *(const uint4*)(gp + 8);
      } else {
        for (int i = 0; i < 16; ++i) {
          int k = k0 + sch * 16 + i;
          lp[i] = (k < K) ? gp[i] : (u16)0;
        }
      }
    }
    {
      const u16* gp = B + (size_t)(bn0 + srow) * K + k0 + sch * 16;
      u16* lp = &Bs[srow * LDT + sch * 16];
      if (k0 + BK <= K) {
        *(uint4*)lp = *(const uint4*)gp;
        *(uint4*)(lp + 8) = *(const uint4*)(gp + 8);
      } else {
        for (int i = 0; i < 16; ++i) {
          int k = k0 + sch * 16 + i;
          lp[i] = (k < K) ? gp[i] : (u16)0;
        }
      }
    }
    __syncthreads();

    bf16x8 af[4], bfr[4];
#pragma unroll
    for (int mi = 0; mi < 4; ++mi)
      af[mi] = *(const bf16x8*)&As[(wm + mi * 16 + lr) * LDT + kg * 8];
#pragma unroll
    for (int ni = 0; ni < 4; ++ni)
      bfr[ni] = *(const bf16x8*)&Bs[(wn + ni * 16 + lr) * LDT + kg * 8];
#pragma unroll
    for (int mi = 0; mi < 4; ++mi)
#pragma unroll
      for (int ni = 0; ni < 4; ++ni)
        acc[mi][ni] = __builtin_amdgcn_mfma_f32_16x16x32_bf16(af[mi], bfr[ni], acc[mi][ni], 0, 0, 0);
    __syncthreads();
  }

  // epilogue: D mapping col=lane&15, row=(lane>>4)*4+reg  [m89/m91 verified]
#pragma unroll
  for (int mi = 0; mi < 4; ++mi)
#pragma unroll
    for (int ni = 0; ni < 4; ++ni) {
      int m0 = bm0 + wm + mi * 16 + kg * 4;
      int col = bn0 + wn + ni * 16 + lr;
      float bv = bias ? bias[col] : 0.f;
      if (MODE == 2) {
        // transposed store: [B][N][T], 4 consecutive t per lane -> one 8B store
        int bidx = m0 >> 10, t0 = m0 & 1023;
        u16x4 pk;
#pragma unroll
        for (int r = 0; r < 4; ++r) pk[r] = f2bf((acc[mi][ni][r] + bv) * scale);
        *(u16x4*)((u16*)Cout + (size_t)bidx * N * Tn + (size_t)col * Tn + t0) = pk;
      } else {
#pragma unroll
        for (int r = 0; r < 4; ++r) {
          float v = (acc[mi][ni][r] + bv) * scale;
          if (MODE == 1)
            ((u16*)Cout)[(size_t)(m0 + r) * N + col] = f2bf(v);
          else
            ((float*)Cout)[(size_t)(m0 + r) * N + col] = v;
        }
      }
    }
}

// ---------- transpose oT [B][256][T] -> o [B][T][256] (bf16) ----------
__global__ __launch_bounds__(256) void k_transp(const u16* __restrict__ in,
                                                u16* __restrict__ out) {
  __shared__ u16 tile[64][68];
  int t0 = blockIdx.x * 64, j0 = blockIdx.y * 64, b = blockIdx.z;
  int tx = threadIdx.x & 15, ty = threadIdx.x >> 4;
  const u16* ib = in + (size_t)b * Hn * Tn;
  u16* ob = out + (size_t)b * Tn * Hn;
#pragma unroll
  for (int a = 0; a < 4; ++a) {
    int j = ty + a * 16;
    *(u16x4*)&tile[j][tx * 4] = *(const u16x4*)&ib[(size_t)(j0 + j) * Tn + t0 + tx * 4];
  }
  __syncthreads();
#pragma unroll
  for (int a = 0; a < 4; ++a) {
    int t = ty + a * 16;
    u16x4 v;
    v[0] = tile[tx * 4 + 0][t];
    v[1] = tile[tx * 4 + 1][t];
    v[2] = tile[tx * 4 + 2][t];
    v[3] = tile[tx * 4 + 3][t];
    *(u16x4*)&ob[(size_t)(t0 + t) * Hn + j0 + tx * 4] = v;
  }
}

// ---------- GRU scan (VALU dot2 core, chunked I/O, raw barriers) ----------
// One workgroup (768 thr = 12 waves) per chain. Thread tau: quad-slice —
// quarter q=tau&3 of k, rows {r0,+192,+384,+576}, r0=tau>>2; weights 128 u32
// register-resident. h in LDS quarter-interleaved (R3 layout). Per step: only
// LDS ops; x comes from a 16B/8-step register chunk (from transposed xg),
// h goes out as a 16B/8-step packed store (to transposed oT). Raw s_barrier
// keeps those global ops in flight across steps (no vmcnt(0) drain).
__global__ void __launch_bounds__(768)
__attribute__((amdgpu_waves_per_eu(3, 3)))
k_gru(const u32* __restrict__ Wp,
      const float* __restrict__ bhh,
      const u16* __restrict__ xgT,   // [B][768][T]
      u16* __restrict__ oT) {        // [B][256][T]
  const int tid = threadIdx.x;
  const int b = blockIdx.x;
  const int q = tid & 3;
  const int r0 = tid >> 2;
  __shared__ __align__(16) f16 hsh[Hn];       // quarter-interleaved
  __shared__ float ght[G3];
  __shared__ __align__(16) u16 xst[G3 * 8];   // x stash: [j][8 steps]

  // weights -> registers, pinned
  u32 wv[128];
  {
    const uint4* wp = (const uint4*)(Wp + (size_t)tid * 128);
#pragma unroll
    for (int i = 0; i < 32; ++i) ((uint4*)wv)[i] = wp[i];
  }
#pragma unroll
  for (int i = 0; i < 128; ++i) asm volatile("" : "+v"(wv[i]));

  float b0 = 0.f, b1 = 0.f, b2 = 0.f;
  int hidx = 0;
  if (tid < Hn) {
    b0 = bhh[tid]; b1 = bhh[tid + Hn]; b2 = bhh[tid + 2 * Hn];
    hidx = (tid & 7) + ((tid >> 3) & 7) * 32 + (tid >> 6) * 8;
  }
  float hreg = 0.f;
  if (tid < 128) ((h2*)hsh)[tid] = h2{(f16)0.f, (f16)0.f};

  const u16* xrow = xgT + (size_t)b * G3 * Tn + (size_t)tid * Tn;  // this thread's gate row
  u16* obT = oT + (size_t)b * Hn * Tn + (size_t)tid * Tn;          // gate threads only
  const f16* hbase = hsh + q * 8;

  uint4 xchunk = *(const uint4*)xrow;   // chunk 0 (steps 0..7)
  u32 hw4[4];
  __syncthreads();   // covers hsh init (one-time; drain OK here)

  for (int tc = 0; tc < Tn / 8; ++tc) {
    // stash this chunk for gate readers (visible after first lds_barrier below)
    *(uint4*)&xst[tid * 8] = xchunk;
    // prefetch next chunk (stays in flight across raw barriers)
    int tcn = (tc + 1 < Tn / 8) ? tc + 1 : tc;
    xchunk = *(const uint4*)(xrow + tcn * 8);

#pragma unroll
    for (int u = 0; u < 8; ++u) {
      // ---- dot phase: 8 rounds x (1 ds_read_b128 + 16 dot2) ----
      float acc0 = 0.f, acc1 = 0.f, acc2 = 0.f, acc3 = 0.f;
#pragma unroll
      for (int i = 0; i < 8; ++i) {
        h8 hv = *(const h8*)(hbase + i * 32);
        h2 p0 = __builtin_shufflevector(hv, hv, 0, 1);
        h2 p1 = __builtin_shufflevector(hv, hv, 2, 3);
        h2 p2 = __builtin_shufflevector(hv, hv, 4, 5);
        h2 p3 = __builtin_shufflevector(hv, hv, 6, 7);
        acc0 = fdot2f(W2(wv[i * 4 + 0]), p0, acc0);
        acc0 = fdot2f(W2(wv[i * 4 + 1]), p1, acc0);
        acc0 = fdot2f(W2(wv[i * 4 + 2]), p2, acc0);
        acc0 = fdot2f(W2(wv[i * 4 + 3]), p3, acc0);
        acc1 = fdot2f(W2(wv[32 + i * 4 + 0]), p0, acc1);
        acc1 = fdot2f(W2(wv[32 + i * 4 + 1]), p1, acc1);
        acc1 = fdot2f(W2(wv[32 + i * 4 + 2]), p2, acc1);
        acc1 = fdot2f(W2(wv[32 + i * 4 + 3]), p3, acc1);
        acc2 = fdot2f(W2(wv[64 + i * 4 + 0]), p0, acc2);
        acc2 = fdot2f(W2(wv[64 + i * 4 + 1]), p1, acc2);
        acc2 = fdot2f(W2(wv[64 + i * 4 + 2]), p2, acc2);
        acc2 = fdot2f(W2(wv[64 + i * 4 + 3]), p3, acc2);
        acc3 = fdot2f(W2(wv[96 + i * 4 + 0]), p0, acc3);
        acc3 = fdot2f(W2(wv[96 + i * 4 + 1]), p1, acc3);
        acc3 = fdot2f(W2(wv[96 + i * 4 + 2]), p2, acc3);
        acc3 = fdot2f(W2(wv[96 + i * 4 + 3]), p3, acc3);
      }
      acc0 = qsum(acc0); acc1 = qsum(acc1); acc2 = qsum(acc2); acc3 = qsum(acc3);
      float sel = (q == 0) ? acc0 : (q == 1) ? acc1 : (q == 2) ? acc2 : acc3;
      ght[r0 + 192 * q] = sel;
      lds_barrier();

      // ---- gate phase (waves 0-3) ----
      if (tid < Hn) {
        float gr = ght[tid] + b0;
        float gz = ght[tid + Hn] + b1;
        float gn = ght[tid + 2 * Hn] + b2;
        float xr = bf2f(xst[tid * 8 + u]);
        float xz = bf2f(xst[(tid + Hn) * 8 + u]);
        float xn = bf2f(xst[(tid + 2 * Hn) * 8 + u]);
        float r = fsig(xr + gr);
        float z = fsig(xz + gz);
        float n = ftanh(xn + r * gn);
        hreg = (1.f - z) * n + z * hreg;
        u16 hb16 = f2bf(hreg);
        if ((u & 1) == 0) hw4[u >> 1] = hb16;
        else hw4[u >> 1] |= ((u32)hb16) << 16;
        hsh[hidx] = (f16)hreg;
      }
      lds_barrier();
    }

    // one 16B store per 8 steps (in flight across barriers; no drain)
    if (tid < Hn) {
      uint4 s; s.x = hw4[0]; s.y = hw4[1]; s.z = hw4[2]; s.w = hw4[3];
      *(uint4*)(obT + tc * 8) = s;
    }
  }
}

// ---------- attention over 5 style tokens ----------
__global__ __launch_bounds__(256) void k_attn(const u16* __restrict__ q,
                                              const float* __restrict__ kv,
                                              u16* __restrict__ ctx) {
  __shared__ float ks[STOK * Hn], vs[STOK * Hn];
  int tid = threadIdx.x;
  for (int i = tid; i < STOK * Hn; i += 256) {
    ks[i] = kv[i];
    vs[i] = kv[STOK * Hn + i];
  }
  __syncthreads();
  size_t row = (size_t)blockIdx.x * 256 + tid;
  const u16* qr = q + row * Hn;
  u16* cr = ctx + row * Hn;
#pragma unroll
  for (int h = 0; h < 4; ++h) {
    float sc[STOK] = {0.f, 0.f, 0.f, 0.f, 0.f};
    for (int d = 0; d < 64; ++d) {
      float qv = bf2f(qr[h * 64 + d]);
#pragma unroll
      for (int s = 0; s < STOK; ++s) sc[s] += qv * ks[s * Hn + h * 64 + d];
    }
    float m = sc[0];
#pragma unroll
    for (int s = 1; s < STOK; ++s) m = fmaxf(m, sc[s]);
    float p[STOK], sum = 0.f;
#pragma unroll
    for (int s = 0; s < STOK; ++s) { p[s] = __expf(sc[s] - m); sum += p[s]; }
    float inv = 1.f / sum;
    for (int e = 0; e < 64; ++e) {
      float c = 0.f;
#pragma unroll
      for (int s = 0; s < STOK; ++s) c += p[s] * vs[s * Hn + h * 64 + e];
      cr[h * 64 + e] = f2bf(c * inv);
    }
  }
}

// ---------- workspace layout (bytes) ----------
#define WS_XGT  ((size_t)0)                         // xg^T [B][768][T] bf16 = 100,663,296
#define WS_OT   ((size_t)100663296)                 // oT [B][256][T] bf16 = 33,554,432
#define WS_O    ((size_t)134217728)                 // o  [B][T][256] bf16 = 33,554,432 (o0 then o1)
#define WS_FB   ((size_t)167772160)                 // feats bf16 = 10,485,760
#define WS_W0   ((size_t)178257920)                 // Wih0 bf16 = 122,880
#define WS_W1   ((size_t)178380800)                 // Wih1 bf16 = 393,216
#define WS_QW   ((size_t)178774016)                 // q_w bf16 = 131,072
#define WS_OW   ((size_t)178905088)                 // out_w bf16 = 131,072
#define WS_H0   ((size_t)179036160)                 // Whh0 prepped = 393,216
#define WS_H1   ((size_t)179429376)                 // Whh1 prepped = 393,216
#define WS_KV   ((size_t)179822592)                 // k,v f32 = 10,240
// aliases into the (dead-by-then) xgT region:
#define WS_QB   ((size_t)0)                         // q [B*T][256] bf16
#define WS_CTX  ((size_t)33554432)                  // ctx [B*T][256] bf16

extern "C" void kernel_launch(void* const* d_in, const int* in_sizes, int n_in,
                              void* d_out, int out_size, void* d_ws, size_t ws_size,
                              hipStream_t stream) {
  const float* feats = (const float*)d_in[0];
  const float* style = (const float*)d_in[1];
  const float* Wih0 = (const float*)d_in[2];
  const float* Whh0 = (const float*)d_in[3];
  const float* bih0 = (const float*)d_in[4];
  const float* bhh0 = (const float*)d_in[5];
  const float* Wih1 = (const float*)d_in[6];
  const float* Whh1 = (const float*)d_in[7];
  const float* bih1 = (const float*)d_in[8];
  const float* bhh1 = (const float*)d_in[9];
  const float* q_w = (const float*)d_in[10];
  const float* k_w = (const float*)d_in[11];
  const float* v_w = (const float*)d_in[12];
  const float* in_b = (const float*)d_in[13];
  const float* out_w = (const float*)d_in[14];
  const float* out_b = (const float*)d_in[15];

  char* ws = (char*)d_ws;
  u16* xgT = (u16*)(ws + WS_XGT);
  u16* oT = (u16*)(ws + WS_OT);
  u16* o = (u16*)(ws + WS_O);
  u16* fb = (u16*)(ws + WS_FB);
  u16* w0 = (u16*)(ws + WS_W0);
  u16* w1 = (u16*)(ws + WS_W1);
  u16* qw = (u16*)(ws + WS_QW);
  u16* ow = (u16*)(ws + WS_OW);
  u32* h0 = (u32*)(ws + WS_H0);
  u32* h1 = (u32*)(ws + WS_H1);
  float* kv = (float*)(ws + WS_KV);
  u16* qb = (u16*)(ws + WS_QB);
  u16* ctx = (u16*)(ws + WS_CTX);

  auto cvgrid = [](int n) { int g = (n + 255) / 256; return g > 2048 ? 2048 : g; };

  // conversions / weight prep
  k_cvt_bf16<<<cvgrid(MROWS * IDIM), 256, 0, stream>>>(feats, fb, MROWS * IDIM);
  k_cvt_bf16<<<cvgrid(G3 * IDIM), 256, 0, stream>>>(Wih0, w0, G3 * IDIM);
  k_cvt_bf16<<<cvgrid(G3 * Hn), 256, 0, stream>>>(Wih1, w1, G3 * Hn);
  k_cvt_bf16<<<cvgrid(Hn * Hn), 256, 0, stream>>>(q_w, qw, Hn * Hn);
  k_cvt_bf16<<<cvgrid(Hn * Hn), 256, 0, stream>>>(out_w, ow, Hn * Hn);
  k_prep_whh<<<(G3 * 128 + 255) / 256, 256, 0, stream>>>(Whh0, h0);
  k_prep_whh<<<(G3 * 128 + 255) / 256, 256, 0, stream>>>(Whh1, h1);

  k_kv<<<1, 256, 0, stream>>>(style, k_w, v_w, in_b, kv);

  dim3 g768(MROWS / 128, G3 / 128);
  dim3 g256(MROWS / 128, Hn / 128);
  dim3 gtr(Tn / 64, Hn / 64, Bn);

  // layer 0
  k_gemm_bt<2><<<g768, 256, 0, stream>>>(fb, w0, bih0, 1.f, xgT, MROWS, G3, IDIM);
  k_gru<<<Bn, G3, 0, stream>>>(h0, bhh0, xgT, oT);
  k_transp<<<gtr, 256, 0, stream>>>(oT, o);
  // layer 1
  k_gemm_bt<2><<<g768, 256, 0, stream>>>(o, w1, bih1, 1.f, xgT, MROWS, G3, Hn);
  k_gru<<<Bn, G3, 0, stream>>>(h1, bhh1, xgT, oT);
  k_transp<<<gtr, 256, 0, stream>>>(oT, o);
  // attention
  k_gemm_bt<1><<<g256, 256, 0, stream>>>(o, qw, in_b, 0.125f, qb, MROWS, Hn, Hn);
  k_attn<<<MROWS / 256, 256, 0, stream>>>(qb, kv, ctx);
  // output projection
  k_gemm_bt<0><<<g256, 256, 0, stream>>>(ctx, ow, out_b, 1.f, d_out, MROWS, Hn, Hn);
}